// Round 4
// baseline (43.552 us; speedup 1.0000x reference)
//
#include <hip/hip_runtime.h>

typedef float f32x2 __attribute__((ext_vector_type(2)));

#define NPTS 8192
#define THREADS 256
#define PPT 8                   // points per thread
#define PPB (THREADS * PPT)     // 2048 points per block
#define PBLKS (NPTS / PPB)      // 4 point-blocks
#define NCHUNK 32               // candidate chunks
#define CAND (NPTS / NCHUNK)    // 256 candidates per chunk
#define WSROW (6 * NPTS)        // floats per chunk-slice: 49152
#define RED1BLKS 192            // 49152 points / 256 threads
#define RED1THREADS 256

// Kernel 1: per (channel, direction, point-block, candidate-chunk) block,
// compute partial min |x - c| over this chunk's candidates into a chunk-private
// ws slice. Inner loop: candidates staged NEGATED as pairs in LDS, so each
// 2-candidate step is v_pk_add_f32 (d0,d1)=(x,x)+(-c0,-c1) + v_min3 with abs
// modifiers = 1.0 VALU per pair (the CDNA packed-f32 trick).
__global__ __launch_bounds__(THREADS) void chamfer_min_kernel(
    const float* __restrict__ pred, const float* __restrict__ target,
    float* __restrict__ ws)
{
    int b = blockIdx.x;
    const int ck  = b & (NCHUNK - 1); b >>= 5;
    const int pb  = b & (PBLKS - 1);  b >>= 2;
    const int dir = b & 1;            b >>= 1;
    const int ch  = b;                // 0..2

    const float* pts  = dir ? target : pred;   // dir=0: pred->target
    const float* cnds = dir ? pred   : target;

    __shared__ f32x2 s2[CAND / 2];             // negated candidates, paired
    const int t = threadIdx.x;
    for (int k = t; k < CAND; k += THREADS)
        ((float*)s2)[k] = -cnds[(ck * CAND + k) * 3 + ch];

    f32x2 x2[PPT];
    float m[PPT];
    #pragma unroll
    for (int p = 0; p < PPT; ++p) {
        const float x = pts[(pb * PPB + p * THREADS + t) * 3 + ch];
        x2[p].x = x; x2[p].y = x;
        m[p] = 3.0e38f;
    }
    __syncthreads();

    #pragma unroll 4
    for (int k2 = 0; k2 < CAND / 2; ++k2) {
        const f32x2 c2 = s2[k2];               // ds_read_b64 broadcast
        #pragma unroll
        for (int p = 0; p < PPT; ++p) {
            f32x2 d;
            asm("v_pk_add_f32 %0, %1, %2" : "=v"(d) : "v"(x2[p]), "v"(c2));
            m[p] = fminf(m[p], fminf(fabsf(d.x), fabsf(d.y)));  // v_min3 |.|,|.|
        }
    }

    float* w = ws + (size_t)ck * WSROW + (ch * 2 + dir) * NPTS + pb * PPB;
    #pragma unroll
    for (int p = 0; p < PPT; ++p)
        w[p * THREADS + t] = m[p];
}

// Stage 1 reduce: 192 blocks, 1 point per thread; min over the 32 chunk
// slices (coalesced: warp reads 256 contiguous floats per slice iteration),
// then block-sum -> 1 partial per block.
__global__ __launch_bounds__(RED1THREADS) void chamfer_red1_kernel(
    const float* __restrict__ ws, float* __restrict__ partials)
{
    const int t = threadIdx.x;
    const int g = blockIdx.x * RED1THREADS + t;   // point id in [0, 49152)

    float mn = 3.0e38f;
    #pragma unroll 8
    for (int ck = 0; ck < NCHUNK; ++ck)
        mn = fminf(mn, ws[(size_t)ck * WSROW + g]);

    float sum = mn;
    #pragma unroll
    for (int off = 32; off > 0; off >>= 1)
        sum += __shfl_down(sum, off, 64);

    __shared__ float wsum[RED1THREADS / 64];
    if ((t & 63) == 0) wsum[t >> 6] = sum;
    __syncthreads();
    if (t == 0) {
        float tot = 0.f;
        #pragma unroll
        for (int w = 0; w < RED1THREADS / 64; ++w) tot += wsum[w];
        partials[blockIdx.x] = tot;
    }
}

// Stage 2 reduce: one block sums the 192 partials and scales by 1/NPTS.
__global__ __launch_bounds__(256) void chamfer_red2_kernel(
    const float* __restrict__ partials, float* __restrict__ out)
{
    const int t = threadIdx.x;
    float sum = (t < RED1BLKS) ? partials[t] : 0.f;
    #pragma unroll
    for (int off = 32; off > 0; off >>= 1)
        sum += __shfl_down(sum, off, 64);

    __shared__ float wsum[4];
    if ((t & 63) == 0) wsum[t >> 6] = sum;
    __syncthreads();
    if (t == 0) {
        float tot = (wsum[0] + wsum[1]) + (wsum[2] + wsum[3]);
        out[0] = tot * (1.0f / NPTS);
    }
}

extern "C" void kernel_launch(void* const* d_in, const int* in_sizes, int n_in,
                              void* d_out, int out_size, void* d_ws, size_t ws_size,
                              hipStream_t stream) {
    const float* pred   = (const float*)d_in[0];
    const float* target = (const float*)d_in[1];
    float* out = (float*)d_out;
    float* ws = (float*)d_ws;                               // [NCHUNK][6][NPTS]
    float* partials = ws + (size_t)NCHUNK * WSROW;          // [RED1BLKS]

    chamfer_min_kernel<<<3 * 2 * PBLKS * NCHUNK, THREADS, 0, stream>>>(pred, target, ws);
    chamfer_red1_kernel<<<RED1BLKS, RED1THREADS, 0, stream>>>(ws, partials);
    chamfer_red2_kernel<<<1, 256, 0, stream>>>(partials, out);
}

// Round 5
// 26.029 us; speedup vs baseline: 1.6732x; 1.6732x over previous
//
#include <hip/hip_runtime.h>

#define NPTS 8192
#define THREADS 256             // 4 waves
#define NWAVE 4
#define QCAND (NPTS / NWAVE)    // 2048 candidates per wave (quarter)
#define PGRPS 128               // point-groups of 64 points
#define NBLK (6 * PGRPS)        // 768 blocks

// Kernel A: block = (ch,dir) x point-group(64 points). All 8192 candidates
// staged in LDS; lane -> point, wave -> candidate-quarter. Wave-uniform
// float4 LDS broadcast + two independent v_min3(|.|,|.|) chains
// (1.5 VALU/pair). Cross-wave min + wave0 sum -> one partial per block.
__global__ __launch_bounds__(THREADS) void chamfer_block_kernel(
    const float* __restrict__ pred, const float* __restrict__ target,
    float* __restrict__ partials)
{
    const int b  = blockIdx.x;
    const int pg = b & (PGRPS - 1);
    const int c  = b >> 7;            // 0..5
    const int dir = c & 1;
    const int ch  = c >> 1;           // 0..2

    const float* pts  = dir ? target : pred;
    const float* cnds = dir ? pred   : target;

    __shared__ float s[NPTS];         // 32 KB candidate stage
    __shared__ float xm[NWAVE][64];   // cross-wave min combine

    const int t    = threadIdx.x;
    const int lane = t & 63;
    const int wave = t >> 6;

    // Stage candidates (stride-3 gather; source is L2-resident).
    #pragma unroll
    for (int i = 0; i < NPTS / THREADS; ++i)
        s[t + i * THREADS] = cnds[(t + i * THREADS) * 3 + ch];

    const float x = pts[(pg * 64 + lane) * 3 + ch];
    __syncthreads();

    const float4* s4 = (const float4*)(s + wave * QCAND);
    float m0 = 3.0e38f, m1 = 3.0e38f;
    #pragma unroll 8
    for (int i = 0; i < QCAND / 4; ++i) {
        const float4 cv = s4[i];                       // wave-uniform broadcast
        m0 = fminf(m0, fminf(fabsf(x - cv.x), fabsf(x - cv.y)));
        m1 = fminf(m1, fminf(fabsf(x - cv.z), fabsf(x - cv.w)));
    }
    xm[wave][lane] = fminf(m0, m1);
    __syncthreads();

    if (wave == 0) {
        float m = fminf(fminf(xm[0][lane], xm[1][lane]),
                        fminf(xm[2][lane], xm[3][lane]));
        // sum the 64 point-mins across the wave
        #pragma unroll
        for (int off = 32; off > 0; off >>= 1)
            m += __shfl_down(m, off, 64);
        if (lane == 0) partials[b] = m;
    }
}

// Kernel B: one block sums the 768 block-partials -> out = sum / NPTS.
__global__ __launch_bounds__(THREADS) void chamfer_final_kernel(
    const float* __restrict__ partials, float* __restrict__ out)
{
    const int t = threadIdx.x;
    float sum = partials[t] + partials[t + 256] + partials[t + 512];

    #pragma unroll
    for (int off = 32; off > 0; off >>= 1)
        sum += __shfl_down(sum, off, 64);

    __shared__ float wsum[NWAVE];
    if ((t & 63) == 0) wsum[t >> 6] = sum;
    __syncthreads();
    if (t == 0) {
        float tot = (wsum[0] + wsum[1]) + (wsum[2] + wsum[3]);
        out[0] = tot * (1.0f / NPTS);
    }
}

extern "C" void kernel_launch(void* const* d_in, const int* in_sizes, int n_in,
                              void* d_out, int out_size, void* d_ws, size_t ws_size,
                              hipStream_t stream) {
    const float* pred   = (const float*)d_in[0];
    const float* target = (const float*)d_in[1];
    float* out = (float*)d_out;
    float* partials = (float*)d_ws;   // [NBLK]

    chamfer_block_kernel<<<NBLK, THREADS, 0, stream>>>(pred, target, partials);
    chamfer_final_kernel<<<1, THREADS, 0, stream>>>(partials, out);
}